// Round 1
// baseline (1458.020 us; speedup 1.0000x reference)
//
#include <hip/hip_runtime.h>
#include <hip/hip_bf16.h>
#include <hip/hip_fp16.h>

#define SEQ   320
#define GATES 1600
#define NCOL  3200
#define GDW   25    // workgroups per direction in the recurrent kernel
#define RPW   16    // h-rows owned per workgroup (400/25)

typedef _Float16 half2v __attribute__((ext_vector_type(2)));
typedef _Float16 f16x8  __attribute__((ext_vector_type(8)));
typedef float    f32x4  __attribute__((ext_vector_type(4)));
union H2U { unsigned u; half2v h; __half2 hh; };

// ---------------------------------------------------------------- prep: embed->f16, bias sums, cvt W_ih_l0
__global__ __launch_bounds__(256) void prep_kernel(
    const int* __restrict__ words, const int* __restrict__ tags,
    const float* __restrict__ wemb, const float* __restrict__ temb,
    _Float16* __restrict__ Ah0,
    const float* __restrict__ bihl0,  const float* __restrict__ bhhl0,
    const float* __restrict__ bihl0r, const float* __restrict__ bhhl0r,
    const float* __restrict__ bihl1,  const float* __restrict__ bhhl1,
    const float* __restrict__ bihl1r, const float* __restrict__ bhhl1r,
    const float* __restrict__ mlpb1,
    float* __restrict__ bL0, float* __restrict__ bL1, float* __restrict__ bAB,
    const float* __restrict__ wih0, const float* __restrict__ wih0r,
    _Float16* __restrict__ BhA)
{
    const int b = blockIdx.x, t = threadIdx.x;
    if (b < 520) {                       // embeddings -> Ah0 (320 x 416, zero-pad)
        int i = b * 256 + t;
        if (i >= SEQ * 416) return;
        int tt = i / 416, c = i % 416;
        float v = 0.f;
        if (c < 300)      v = wemb[(size_t)words[tt] * 300 + c];
        else if (c < 400) v = temb[(size_t)tags[tt] * 100 + (c - 300)];
        Ah0[i] = (_Float16)v;
    } else if (b < 533) {                // bias sums
        int g = (b - 520) * 256 + t;
        if (g >= NCOL) return;
        if (g < GATES) {
            bL0[g] = bihl0[g] + bhhl0[g];
            bL1[g] = bihl1[g] + bhhl1[g];
            bAB[g] = mlpb1[g];
        } else {
            int q = g - GATES;
            bL0[g] = bihl0r[q] + bhhl0r[q];
            bL1[g] = bihl1r[q] + bhhl1r[q];
            bAB[g] = 0.f;
        }
    } else {                             // W_ih_l0 -> fp16 (3200 x 416, zero-pad K)
        int i = (b - 533) * 256 + t;
        if (i >= NCOL * 416) return;
        int n = i / 416, k = i % 416;
        float v = 0.f;
        if (k < 400)
            v = (n < GATES) ? wih0[(size_t)n * 400 + k]
                            : wih0r[(size_t)(n - GATES) * 400 + k];
        BhA[i] = (_Float16)v;
    }
}

// ---------------------------------------------------------------- cvt W_ih_l1 -> BhB, mlp_w1 -> BhA
__global__ __launch_bounds__(256) void cvt2_kernel(
    const float* __restrict__ wih1, const float* __restrict__ wih1r,
    _Float16* __restrict__ BhB,
    const float* __restrict__ mlpw1, _Float16* __restrict__ BhA)
{
    const int b = blockIdx.x, t = threadIdx.x;
    if (b < 10000) {
        int i = b * 256 + t;
        if (i >= NCOL * 800) return;
        int n = i / 800, k = i % 800;
        BhB[i] = (_Float16)((n < GATES) ? wih1[(size_t)n * 800 + k]
                                        : wih1r[(size_t)(n - GATES) * 800 + k]);
    } else {
        int i = (b - 10000) * 256 + t;
        if (i >= NCOL * 800) return;
        int n = i / 800, k = i % 800;
        BhA[i] = (_Float16)((n < GATES) ? mlpw1[(size_t)n * 1600 + k]
                                        : mlpw1[(size_t)(n - GATES) * 1600 + 800 + k]);
    }
}

// ---------------------------------------------------------------- MFMA f16 GEMM (as R6, verified)
__global__ __launch_bounds__(256) void gemm_f16(
    const _Float16* __restrict__ A, int Kp,
    const _Float16* __restrict__ B,
    const float* __restrict__ bias, float* __restrict__ C)
{
    const int tid  = threadIdx.x;
    const int w    = tid >> 6, lane = tid & 63;
    const int quad = lane >> 4, l16 = lane & 15;
    const int mb   = blockIdx.y * 32 + (w & 1) * 16;
    const int n0   = blockIdx.x * 64 + (w >> 1) * 32;
    const _Float16* Arow = A + (size_t)(mb + l16) * Kp + quad * 8;
    const _Float16* B0r  = B + (size_t)(n0 + l16) * Kp + quad * 8;
    const _Float16* B1r  = B0r + (size_t)16 * Kp;
    f32x4 acc0 = {0.f, 0.f, 0.f, 0.f}, acc1 = {0.f, 0.f, 0.f, 0.f};
#pragma unroll 4
    for (int k0 = 0; k0 < Kp; k0 += 32) {
        f16x8 a  = *(const f16x8*)(Arow + k0);
        f16x8 b0 = *(const f16x8*)(B0r + k0);
        f16x8 b1 = *(const f16x8*)(B1r + k0);
        acc0 = __builtin_amdgcn_mfma_f32_16x16x32_f16(a, b0, acc0, 0, 0, 0);
        acc1 = __builtin_amdgcn_mfma_f32_16x16x32_f16(a, b1, acc1, 0, 0, 0);
    }
    const int mr = mb + quad * 4;
    float bn0 = bias[n0 + l16], bn1 = bias[n0 + 16 + l16];
#pragma unroll
    for (int r = 0; r < 4; ++r) {
        C[(size_t)(mr + r) * NCOL + n0 + l16]      = acc0[r] + bn0;
        C[(size_t)(mr + r) * NCOL + n0 + 16 + l16] = acc1[r] + bn1;
    }
}

// ---------------------------------------------------------------- recurrence
// R8: one barrier per step. 25 WGs x 256 threads per direction, 16 rows/WG.
// Thread role: rp=tid>>5 (row-pair, 2 rows), g=(tid>>3)&3 (gate), ks=tid&7
// (k-slice of 50 halves). Each (gate,row) dot completes inside one wave:
// ks-reduce via shfl_xor(1,2,4), gate gather via shfl_xor(8,16,24), act
// computed redundantly in all 32 lanes of a row-pair -> no part[] LDS, no
// second barrier. Each thread holds 2 weight rows (50 packed dwords, regs)
// and reads its 25-dword h-slice ONCE (shared by both rows): LDS traffic
// 106KB -> 25KB per step. h_prev LDS double-buffered as 8 slices x 28
// dwords (25 used) so every slice is 16B-aligned for b128 reads.
// Exchange block = 8 packed dwords (one per row-pair) in a 64B line;
// sentinel = 0xFFFFFFFF (|h|<1 => fp16 half never 0xFFFF); the packed
// dword doubles as exchange payload, ah output, and own-row LDS write.
__global__ __launch_bounds__(256) void lstm_layer(
    const float* __restrict__ gates,   // SEQ x 3200 (x@W_ih^T + biases)
    const float* __restrict__ whh_f, const float* __restrict__ whh_b,
    const float* __restrict__ h0f, const float* __restrict__ h0b,
    const float* __restrict__ c0f, const float* __restrict__ c0b,
    unsigned* __restrict__ ex,         // exchange region (re-sentineled per layer)
    _Float16* __restrict__ ah)         // SEQ x 800 fp16 h (input to next GEMM)
{
    __shared__ __align__(16) unsigned hbuf[2][224];  // 8 slices x 28 dwords, dbuf
    const int tid = threadIdx.x;
    const int dir = blockIdx.x >= GDW;
    const int wg  = blockIdx.x - dir * GDW;
    const float* whh = dir ? whh_b : whh_f;
    const float* h0d = dir ? h0b : h0f;
    const float* c0d = dir ? c0b : c0f;

    const int rp = tid >> 5;           // row-pair 0..7 -> rows {2rp, 2rp+1}
    const int g  = (tid >> 3) & 3;     // gate
    const int ks = tid & 7;            // k-slice (50 halves = 25 dwords)
    const int jA = wg * RPW + 2 * rp;  // first owned row (within direction)

    // persistent fp16 weights: 2 rows x 50 halves, packed 25 dwords each
    unsigned wrA[25], wrB[25];
    {
        const float2* wA = (const float2*)(whh + ((size_t)g * 400 + jA) * 400 + 50 * ks);
        const float2* wB = (const float2*)(whh + ((size_t)g * 400 + jA + 1) * 400 + 50 * ks);
#pragma unroll
        for (int i = 0; i < 25; ++i) {
            float2 fa = wA[i], fb = wB[i];
            H2U ca, cbu;
            ca.hh  = __floats2half2_rn(fa.x, fa.y);
            cbu.hh = __floats2half2_rn(fb.x, fb.y);
            wrA[i] = ca.u; wrB[i] = cbu.u;
        }
    }

    // poll constants (192 pollers: 24 remote blocks x 8 dwords)
    int bp = 0, pollq = 0;
    if (tid < 192) {
        bp = tid >> 3; bp += (bp >= wg);
        int q = bp * 8 + (tid & 7);            // global h-dword index
        pollq = (q / 25) * 28 + q % 25;        // constant LDS slot
    }
    const int qown    = wg * 8 + rp;
    const int ownaddr = (qown / 25) * 28 + qown % 25;
    const float* gbase = gates + dir * GATES + g * 400 + jA;
    unsigned* exq = ex + ((size_t)(dir * GDW + wg) * SEQ) * 16 + rp;
    unsigned* ahq = (unsigned*)ah + dir * 200 + wg * 8 + rp;

    float cA = c0d[jA], cB = c0d[jA + 1];

    for (int s = 0; s < SEQ; ++s) {
        const int row = dir ? (SEQ - 1 - s) : s;
        const int cb  = s & 1;
        // gate prefetch (independent of h_prev, overlaps the poll)
        float2 gv = *(const float2*)(gbase + (size_t)row * NCOL);

        if (s == 0) {
            if (tid < 200) {
                float2 f = ((const float2*)h0d)[tid];
                H2U a; a.hh = __floats2half2_rn(f.x, f.y);
                hbuf[0][(tid / 25) * 28 + tid % 25] = a.u;
            }
        } else if (tid < 192) {
            const int rprev = dir ? row + 1 : row - 1;
            const unsigned* src = ex + (((size_t)dir * GDW + bp) * SEQ + rprev) * 16 + (tid & 7);
            unsigned v;
            do {
                v = __hip_atomic_load(src, __ATOMIC_RELAXED, __HIP_MEMORY_SCOPE_AGENT);
            } while (v == 0xFFFFFFFFu);
            hbuf[cb][pollq] = v;
        }
        __syncthreads();   // the ONLY barrier in the step

        // dot: 25 dwords (6x b128 + 1x b32), reused for both rows
        const unsigned* hb = &hbuf[cb][ks * 28];
        float accA = 0.f, accB = 0.f;
#pragma unroll
        for (int i = 0; i < 6; ++i) {
            uint4 hq = *(const uint4*)(hb + 4 * i);
            H2U x0, x1, x2, x3, wa, wb;
            x0.u = hq.x; x1.u = hq.y; x2.u = hq.z; x3.u = hq.w;
            wa.u = wrA[4*i+0]; wb.u = wrB[4*i+0];
            accA = __builtin_amdgcn_fdot2(wa.h, x0.h, accA, false);
            accB = __builtin_amdgcn_fdot2(wb.h, x0.h, accB, false);
            wa.u = wrA[4*i+1]; wb.u = wrB[4*i+1];
            accA = __builtin_amdgcn_fdot2(wa.h, x1.h, accA, false);
            accB = __builtin_amdgcn_fdot2(wb.h, x1.h, accB, false);
            wa.u = wrA[4*i+2]; wb.u = wrB[4*i+2];
            accA = __builtin_amdgcn_fdot2(wa.h, x2.h, accA, false);
            accB = __builtin_amdgcn_fdot2(wb.h, x2.h, accB, false);
            wa.u = wrA[4*i+3]; wb.u = wrB[4*i+3];
            accA = __builtin_amdgcn_fdot2(wa.h, x3.h, accA, false);
            accB = __builtin_amdgcn_fdot2(wb.h, x3.h, accB, false);
        }
        {
            H2U xl, wa, wb; xl.u = hb[24];
            wa.u = wrA[24]; wb.u = wrB[24];
            accA = __builtin_amdgcn_fdot2(wa.h, xl.h, accA, false);
            accB = __builtin_amdgcn_fdot2(wb.h, xl.h, accB, false);
        }

        // ks-reduce (8 lanes) then add gate input
        accA += __shfl_xor(accA, 1); accA += __shfl_xor(accA, 2); accA += __shfl_xor(accA, 4);
        accB += __shfl_xor(accB, 1); accB += __shfl_xor(accB, 2); accB += __shfl_xor(accB, 4);
        accA += gv.x; accB += gv.y;

        // gate gather: value of gate t sits at xor-distance (g^t)*8
        float a1 = __shfl_xor(accA, 8), a2 = __shfl_xor(accA, 16), a3 = __shfl_xor(accA, 24);
        float b1 = __shfl_xor(accB, 8), b2 = __shfl_xor(accB, 16), b3 = __shfl_xor(accB, 24);
        float giA = g==0?accA : g==1?a1 : g==2?a2 : a3;
        float gfA = g==1?accA : g==0?a1 : g==3?a2 : a3;
        float ggA = g==2?accA : g==3?a1 : g==0?a2 : a3;
        float goA = g==3?accA : g==2?a1 : g==1?a2 : a3;
        float giB = g==0?accB : g==1?b1 : g==2?b2 : b3;
        float gfB = g==1?accB : g==0?b1 : g==3?b2 : b3;
        float ggB = g==2?accB : g==3?b1 : g==0?b2 : b3;
        float goB = g==3?accB : g==2?b1 : g==1?b2 : b3;

        // activations (redundant in all 32 lanes of the row-pair; consistent)
        float ivA = 1.f / (1.f + __expf(-giA)), fvA = 1.f / (1.f + __expf(-gfA));
        float ovA = 1.f / (1.f + __expf(-goA)), tgA = 1.f - 2.f / (1.f + __expf(2.f * ggA));
        float ivB = 1.f / (1.f + __expf(-giB)), fvB = 1.f / (1.f + __expf(-gfB));
        float ovB = 1.f / (1.f + __expf(-goB)), tgB = 1.f - 2.f / (1.f + __expf(2.f * ggB));
        cA = fvA * cA + ivA * tgA;
        cB = fvB * cB + ivB * tgB;
        float hA = ovA * (1.f - 2.f / (1.f + __expf(2.f * cA)));
        float hB = ovB * (1.f - 2.f / (1.f + __expf(2.f * cB)));

        // one lane per row-pair: exchange store + ah output + own LDS (next buf)
        if ((tid & 31) == 0) {
            H2U pk; pk.hh = __floats2half2_rn(hA, hB);
            __hip_atomic_store(exq + (size_t)row * 16, pk.u,
                               __ATOMIC_RELAXED, __HIP_MEMORY_SCOPE_AGENT);
            ahq[(size_t)row * 400] = pk.u;
            hbuf[cb ^ 1][ownaddr] = pk.u;
        }
        // hazards: pollers(s+1) + own-writes(s) touch hbuf[s+1&1] only;
        // readers(s) touch hbuf[s&1]; writes to hbuf[s&1] at s+2 are ordered
        // after barrier(s+1), which follows all step-s reads. safe.
    }
}

// ---------------------------------------------------------------- fused scorer (+ border rows)
__global__ __launch_bounds__(256) void scores_kernel(
    const float* __restrict__ ab, const float* __restrict__ w2,
    const float* __restrict__ b2, float* __restrict__ out)
{
    if (blockIdx.y == 20) {              // border: row 0 / col 0
        int i = blockIdx.x * 256 + threadIdx.y * 16 + threadIdx.x;
        if (blockIdx.x < 2 && i < 321) {
            out[i]               = (i == 0) ? 1.f : 0.f;
            out[(size_t)i * 321] = (i == 0) ? 1.f : 0.f;
        }
        return;
    }
    __shared__ float a_s[16 * 132];
    __shared__ float b_s[16 * 132];
    __shared__ float w_s[128];
    const int tx = threadIdx.x, ty = threadIdx.y;
    const int tid = ty * 16 + tx;
    const int n0 = blockIdx.y * 16, d0 = blockIdx.x * 16;
    float acc = 0.f;
    for (int kc = 0; kc < 1600; kc += 128) {
        for (int i = tid; i < 16 * 128; i += 256) {
            int r = i >> 7, c = i & 127;
            a_s[r * 132 + c] = ab[(size_t)(n0 + r) * NCOL + kc + c];
            b_s[r * 132 + c] = ab[(size_t)(d0 + r) * NCOL + 1600 + kc + c];
        }
        if (tid < 128) w_s[tid] = w2[kc + tid];
        __syncthreads();
#pragma unroll
        for (int k = 0; k < 128; k += 4) {
            float4 av = *(const float4*)&a_s[ty * 132 + k];
            float4 bv = *(const float4*)&b_s[tx * 132 + k];
            float4 wv = *(const float4*)&w_s[k];
            acc += fmaxf(av.x + bv.x, 0.f) * wv.x;
            acc += fmaxf(av.y + bv.y, 0.f) * wv.y;
            acc += fmaxf(av.z + bv.z, 0.f) * wv.z;
            acc += fmaxf(av.w + bv.w, 0.f) * wv.w;
        }
        __syncthreads();
    }
    int n = n0 + ty, d = d0 + tx;
    out[(size_t)(n + 1) * 321 + (d + 1)] = (n == d) ? 0.f : (acc + b2[0]);
}

// ---------------------------------------------------------------- launcher
extern "C" void kernel_launch(void* const* d_in, const int* in_sizes, int n_in,
                              void* d_out, int out_size, void* d_ws, size_t ws_size,
                              hipStream_t stream)
{
    const int*   words    = (const int*)d_in[0];
    const int*   tags     = (const int*)d_in[1];
    const float* wemb     = (const float*)d_in[3];
    const float* temb     = (const float*)d_in[4];
    const float* h0       = (const float*)d_in[5];
    const float* c0       = (const float*)d_in[6];
    const float* w_ih_l0  = (const float*)d_in[7];
    const float* w_hh_l0  = (const float*)d_in[8];
    const float* b_ih_l0  = (const float*)d_in[9];
    const float* b_hh_l0  = (const float*)d_in[10];
    const float* w_ih_l0r = (const float*)d_in[11];
    const float* w_hh_l0r = (const float*)d_in[12];
    const float* b_ih_l0r = (const float*)d_in[13];
    const float* b_hh_l0r = (const float*)d_in[14];
    const float* w_ih_l1  = (const float*)d_in[15];
    const float* w_hh_l1  = (const float*)d_in[16];
    const float* b_ih_l1  = (const float*)d_in[17];
    const float* b_hh_l1  = (const float*)d_in[18];
    const float* w_ih_l1r = (const float*)d_in[19];
    const float* w_hh_l1r = (const float*)d_in[20];
    const float* b_ih_l1r = (const float*)d_in[21];
    const float* b_hh_l1r = (const float*)d_in[22];
    const float* mlp_w1   = (const float*)d_in[23];
    const float* mlp_b1   = (const float*)d_in[24];
    const float* mlp_w2   = (const float*)d_in[25];
    const float* mlp_b2   = (const float*)d_in[26];
    float* out = (float*)d_out;

    float* ws      = (float*)d_ws;
    float*    gates  = ws;                              // 320*3200 = 1,024,000 f32
    float*    biasL0 = ws + 1024000;
    float*    biasL1 = ws + 1027200;
    float*    biasAB = ws + 1030400;
    unsigned* ex     = (unsigned*)(ws + 1033600);       // 2*25*320*16 = 256,000 u32
    _Float16* Ah0    = (_Float16*)(ws + 1289600);       // 320*416 halves
    _Float16* Ah1    = (_Float16*)(ws + 1356160);       // 320*800 halves
    _Float16* Ah2    = (_Float16*)(ws + 1484160);       // 320*800 halves
    _Float16* BhA    = (_Float16*)(ws + 1612160);       // up to 3200*800 halves
    _Float16* BhB    = (_Float16*)(ws + 2892160);       // 3200*800 halves

    // sentinel-fill the exchange region (data doubles as ready flag)
    hipMemsetAsync(ex, 0xFF, 256000u * 4, stream);

    prep_kernel<<<5733, 256, 0, stream>>>(
        words, tags, wemb, temb, Ah0,
        b_ih_l0, b_hh_l0, b_ih_l0r, b_hh_l0r,
        b_ih_l1, b_hh_l1, b_ih_l1r, b_hh_l1r,
        mlp_b1, biasL0, biasL1, biasAB, w_ih_l0, w_ih_l0r, BhA);

    gemm_f16<<<dim3(50, 10), 256, 0, stream>>>(Ah0, 416, BhA, biasL0, gates);
    cvt2_kernel<<<20000, 256, 0, stream>>>(w_ih_l1, w_ih_l1r, BhB, mlp_w1, BhA);
    lstm_layer<<<2 * GDW, 256, 0, stream>>>(gates, w_hh_l0, w_hh_l0r,
                                            h0, h0 + 400, c0, c0 + 400, ex, Ah1);
    // re-sentinel for layer 1 (stream-ordered after lstm L0)
    hipMemsetAsync(ex, 0xFF, 256000u * 4, stream);
    gemm_f16<<<dim3(50, 10), 256, 0, stream>>>(Ah1, 800, BhB, biasL1, gates);
    lstm_layer<<<2 * GDW, 256, 0, stream>>>(gates, w_hh_l1, w_hh_l1r,
                                            h0 + 800, h0 + 1200, c0 + 800, c0 + 1200,
                                            ex, Ah2);
    gemm_f16<<<dim3(50, 10), 256, 0, stream>>>(Ah2, 800, BhA, biasAB, gates);

    scores_kernel<<<dim3(20, 21), dim3(16, 16), 0, stream>>>(gates, mlp_w2, mlp_b2, out);
}